// Round 1
// baseline (227.464 us; speedup 1.0000x reference)
//
#include <hip/hip_runtime.h>
#include <cstdint>

#define DIN 2048
#define NKEYS 8
#define ROWS 9
#define CHUNK_WORDS 68                 // 64 data + 4 pad words per 64-elem chunk
#define ROW_WORDS (32 * CHUNK_WORDS)   // 2176 words per staged row
#define SCALE_F 0.35355339059327373f
#define EPS_F 1e-6f

// ---------------- pre-kernel: transpose W_q, W_k ([2048,8] -> [8,2048]) ----------------
__global__ void transpose_w_kernel(const float* __restrict__ Wq,
                                   const float* __restrict__ Wk,
                                   float* __restrict__ wt) {
    int idx = blockIdx.x * 256 + threadIdx.x;   // 0..32767
    int m = idx >> 14;                          // 0: Wq, 1: Wk
    int r = idx & 16383;
    int h = r >> 11;                            // 0..7
    int d = r & 2047;                           // 0..2047
    const float* src = m ? Wk : Wq;
    wt[m * 16384 + h * 2048 + d] = src[d * 8 + h];
}

// ---------------- main kernel: one block per (b,s) position ----------------
template <bool TW>
__global__ __launch_bounds__(256, 2)
void router_kernel(const float* __restrict__ x, const float* __restrict__ bax,
                   const float* __restrict__ Wq, const float* __restrict__ bq,
                   const float* __restrict__ Wk, const float* __restrict__ bk,
                   const float* __restrict__ wt, float* __restrict__ out) {
    __shared__ float lds[ROWS * ROW_WORDS];   // 9 padded rows: 78336 B
    __shared__ float red[ROWS * 4 * 8];       // per-row, per-wave, per-h dot partials
    __shared__ float ssb[4 * ROWS];           // per-wave sumsq partials
    __shared__ float fin[ROWS * 8];           // final q/k vectors

    const int t = threadIdx.x;
    const int w = t >> 6;         // wave 0..3
    const int lane = t & 63;
    const int g = t >> 3;         // d-group 0..31 (owns 64 contiguous elements)
    const int h = t & 7;          // hidden column 0..7
    const long p = blockIdx.x;    // position index

    // ---- stage all 9 rows into LDS (reg-staged; 18 outstanding b128 loads) ----
    const float4* xr = (const float4*)(x + p * (long)DIN);
    const float4* br = (const float4*)(bax + p * (long)(NKEYS * DIN));
    float4 v0[ROWS], v1[ROWS];
#pragma unroll
    for (int r = 0; r < ROWS; ++r) {
        const float4* rp = (r == 0) ? xr : (br + (long)(r - 1) * (DIN / 4));
        v0[r] = rp[t];
        v1[r] = rp[t + 256];
    }
    const int o1 = 4 * t + ((t >> 4) << 2);   // padded word offset of element 4*t
    const int o2 = o1 + 1088;                 // element 4*(t+256)
#pragma unroll
    for (int r = 0; r < ROWS; ++r) {
        *(float4*)&lds[r * ROW_WORDS + o1] = v0[r];
        *(float4*)&lds[r * ROW_WORDS + o2] = v1[r];
    }

    // ---- row sumsq partials (computed once during staging, no h-redundancy) ----
    float ssp[ROWS];
#pragma unroll
    for (int r = 0; r < ROWS; ++r) {
        float4 a = v0[r], b = v1[r];
        ssp[r] = a.x * a.x + a.y * a.y + a.z * a.z + a.w * a.w +
                 b.x * b.x + b.y * b.y + b.z * b.z + b.w * b.w;
    }
#pragma unroll
    for (int m = 1; m < 64; m <<= 1) {
#pragma unroll
        for (int r = 0; r < ROWS; ++r) ssp[r] += __shfl_xor(ssp[r], m);
    }
    if (lane == 0) {
#pragma unroll
        for (int r = 0; r < ROWS; ++r) ssb[w * ROWS + r] = ssp[r];
    }

    // ---- load this thread's weight columns (W_k cached across all 8 key rows) ----
    float wqv[64], wkv[64];
    if constexpr (TW) {
        const float4* q4 = (const float4*)(wt + h * 2048 + g * 64);
        const float4* k4 = (const float4*)(wt + 16384 + h * 2048 + g * 64);
#pragma unroll
        for (int j = 0; j < 16; ++j) {
            float4 a = q4[j];
            wqv[4 * j] = a.x; wqv[4 * j + 1] = a.y; wqv[4 * j + 2] = a.z; wqv[4 * j + 3] = a.w;
            float4 b = k4[j];
            wkv[4 * j] = b.x; wkv[4 * j + 1] = b.y; wkv[4 * j + 2] = b.z; wkv[4 * j + 3] = b.w;
        }
    } else {
#pragma unroll
        for (int j = 0; j < 64; ++j) {
            wqv[j] = Wq[(g * 64 + j) * 8 + h];
            wkv[j] = Wk[(g * 64 + j) * 8 + h];
        }
    }

    __syncthreads();   // rows + ssb visible

    // ---- per-row h-column dots from LDS (broadcast reads), g-butterfly reduce ----
#pragma unroll
    for (int r = 0; r < ROWS; ++r) {
        const float* warr = (r == 0) ? wqv : wkv;
        const float4* lr = (const float4*)&lds[r * ROW_WORDS + g * CHUNK_WORDS];
        float4 a4 = make_float4(0.f, 0.f, 0.f, 0.f);
#pragma unroll
        for (int j = 0; j < 16; ++j) {
            float4 xv = lr[j];
            a4.x = fmaf(xv.x, warr[4 * j], a4.x);
            a4.y = fmaf(xv.y, warr[4 * j + 1], a4.y);
            a4.z = fmaf(xv.z, warr[4 * j + 2], a4.z);
            a4.w = fmaf(xv.w, warr[4 * j + 3], a4.w);
        }
        float dot = (a4.x + a4.y) + (a4.z + a4.w);
        dot += __shfl_xor(dot, 8);
        dot += __shfl_xor(dot, 16);
        dot += __shfl_xor(dot, 32);
        if (lane < 8) red[(r * 4 + w) * 8 + lane] = dot;
    }

    __syncthreads();   // red visible

    // ---- build q/k vectors: normalize + bias ----
    if (t < ROWS * 8) {
        int r = t >> 3, hh = t & 7;
        float dt = red[(r * 4 + 0) * 8 + hh] + red[(r * 4 + 1) * 8 + hh] +
                   red[(r * 4 + 2) * 8 + hh] + red[(r * 4 + 3) * 8 + hh];
        float ss = ssb[0 * ROWS + r] + ssb[1 * ROWS + r] + ssb[2 * ROWS + r] + ssb[3 * ROWS + r];
        float rq = rsqrtf(ss + EPS_F);
        float bias = (r == 0) ? bq[hh] : bk[hh];
        fin[t] = fmaf(dt, rq, bias);
    }

    __syncthreads();   // fin visible

    // ---- scores + softmax (tiny serial tail) ----
    if (t == 0) {
        float qv[8];
#pragma unroll
        for (int i = 0; i < 8; ++i) qv[i] = fin[i];
        float sc[8];
        float mx = -1e30f;
#pragma unroll
        for (int n = 0; n < 8; ++n) {
            float s = 0.f;
#pragma unroll
            for (int i = 0; i < 8; ++i) s = fmaf(qv[i], fin[(n + 1) * 8 + i], s);
            s *= SCALE_F;
            sc[n] = s;
            mx = fmaxf(mx, s);
        }
        float den = 0.f;
#pragma unroll
        for (int n = 0; n < 8; ++n) {
            float e = __expf(sc[n] - mx);
            sc[n] = e;
            den += e;
        }
        float inv = 1.f / den;
#pragma unroll
        for (int n = 0; n < 8; ++n) out[p * 8 + n] = sc[n] * inv;
    }
}

extern "C" void kernel_launch(void* const* d_in, const int* in_sizes, int n_in,
                              void* d_out, int out_size, void* d_ws, size_t ws_size,
                              hipStream_t stream) {
    const float* x   = (const float*)d_in[0];
    const float* bax = (const float*)d_in[1];
    const float* Wq  = (const float*)d_in[2];
    const float* bq  = (const float*)d_in[3];
    const float* Wk  = (const float*)d_in[4];
    const float* bk  = (const float*)d_in[5];
    float* out = (float*)d_out;

    const int positions = in_sizes[0] / DIN;   // B*S = 8192
    const size_t wt_bytes = 2u * 16384u * sizeof(float);
    float* wt = (float*)d_ws;

    if (ws_size >= wt_bytes) {
        transpose_w_kernel<<<128, 256, 0, stream>>>(Wq, Wk, wt);
        router_kernel<true><<<positions, 256, 0, stream>>>(x, bax, Wq, bq, Wk, bk, wt, out);
    } else {
        router_kernel<false><<<positions, 256, 0, stream>>>(x, bax, Wq, bq, Wk, bk, nullptr, out);
    }
}

// Round 2
// 132.232 us; speedup vs baseline: 1.7202x; 1.7202x over previous
//
#include <hip/hip_runtime.h>
#include <cstdint>

#define DIN 2048
#define ROWS 9
#define SCALE_F 0.35355339059327373f
#define EPS_F 1e-6f

// One block = 256 threads, grid-stride over positions.
// Thread t owns elements [8t, 8t+8) of every 2048-float row.
// Weights for those 8 elements x all 8 hidden cols = 64 consecutive floats
// of the row-major [2048][8] matrix -> held in VGPRs for the whole kernel.
// No row staging in LDS at all; reductions are in-register shfl butterflies
// plus a tiny 288-float cross-wave LDS exchange.
__global__ __launch_bounds__(256, 2)
void router_kernel(const float* __restrict__ x, const float* __restrict__ bax,
                   const float* __restrict__ Wq, const float* __restrict__ bq,
                   const float* __restrict__ Wk, const float* __restrict__ bk,
                   float* __restrict__ out, int positions) {
    __shared__ float red[ROWS][4][8];   // per-row, per-wave, per-h dot partials
    __shared__ float ssb[ROWS][4];      // per-row, per-wave sumsq partials
    __shared__ float fin[ROWS * 8];     // final q/k vectors

    const int t = threadIdx.x;
    const int w = t >> 6;
    const int lane = t & 63;

    // ---- preload weight slices (constant-indexed -> stays in VGPRs) ----
    float wqk[128];   // [0..63] = Wq slice, [64..127] = Wk slice
    {
        const float4* q4 = (const float4*)(Wq + 64 * t);
        const float4* k4 = (const float4*)(Wk + 64 * t);
#pragma unroll
        for (int j = 0; j < 16; ++j) {
            float4 a = q4[j];
            wqk[4 * j + 0] = a.x; wqk[4 * j + 1] = a.y;
            wqk[4 * j + 2] = a.z; wqk[4 * j + 3] = a.w;
        }
#pragma unroll
        for (int j = 0; j < 16; ++j) {
            float4 b = k4[j];
            wqk[64 + 4 * j + 0] = b.x; wqk[64 + 4 * j + 1] = b.y;
            wqk[64 + 4 * j + 2] = b.z; wqk[64 + 4 * j + 3] = b.w;
        }
    }
    float bias = 0.f;
    if (t < ROWS * 8) bias = (t < 8) ? bq[t & 7] : bk[t & 7];

    for (int p = blockIdx.x; p < positions; p += gridDim.x) {
        // ---- issue all 18 row loads (deep VMEM pipeline) ----
        const float4* xr = (const float4*)(x + (long)p * DIN) + 2 * t;
        const float4* br = (const float4*)(bax + (long)p * (8 * DIN)) + 2 * t;
        float4 v0[ROWS], v1[ROWS];
        v0[0] = xr[0];
        v1[0] = xr[1];
#pragma unroll
        for (int r = 1; r < ROWS; ++r) {
            v0[r] = br[(r - 1) * (DIN / 4)];
            v1[r] = br[(r - 1) * (DIN / 4) + 1];
        }

        float ssv[ROWS];
#pragma unroll
        for (int r = 0; r < ROWS; ++r) {
            const int base = (r == 0) ? 0 : 64;   // r is unroll-constant
            float e[8] = { v0[r].x, v0[r].y, v0[r].z, v0[r].w,
                           v1[r].x, v1[r].y, v1[r].z, v1[r].w };
            // sumsq partial (reduced after the loop, 8 rows share one transpose)
            float ss = e[0] * e[0];
#pragma unroll
            for (int j = 1; j < 8; ++j) ss = fmaf(e[j], e[j], ss);
            ssv[r] = ss;
            // dot partials for all 8 hidden cols over this thread's 8 elements
            float pd[8];
#pragma unroll
            for (int h = 0; h < 8; ++h) pd[h] = e[0] * wqk[base + h];
#pragma unroll
            for (int j = 1; j < 8; ++j)
#pragma unroll
                for (int h = 0; h < 8; ++h)
                    pd[h] = fmaf(e[j], wqk[base + 8 * j + h], pd[h]);
            // in-group-of-8 transpose reduce: 8 channels -> 1 per lane
            float r1[4];
#pragma unroll
            for (int i = 0; i < 4; ++i) {
                float keep = (lane & 1) ? pd[i + 4] : pd[i];
                float send = (lane & 1) ? pd[i] : pd[i + 4];
                r1[i] = keep + __shfl_xor(send, 1);
            }
            float r2[2];
#pragma unroll
            for (int i = 0; i < 2; ++i) {
                float keep = (lane & 2) ? r1[i + 2] : r1[i];
                float send = (lane & 2) ? r1[i] : r1[i + 2];
                r2[i] = keep + __shfl_xor(send, 2);
            }
            float keep = (lane & 4) ? r2[1] : r2[0];
            float send = (lane & 4) ? r2[0] : r2[1];
            float dv = keep + __shfl_xor(send, 4);
            // cross-group (8 groups per wave)
            dv += __shfl_xor(dv, 8);
            dv += __shfl_xor(dv, 16);
            dv += __shfl_xor(dv, 32);
            if (lane < 8)
                red[r][w][((lane & 1) << 2) | (lane & 2) | ((lane & 4) >> 2)] = dv;
        }

        // ---- sumsq reduce: rows 0..7 via one transpose-reduce, row 8 alone ----
        {
            float r1[4];
#pragma unroll
            for (int i = 0; i < 4; ++i) {
                float keep = (lane & 1) ? ssv[i + 4] : ssv[i];
                float send = (lane & 1) ? ssv[i] : ssv[i + 4];
                r1[i] = keep + __shfl_xor(send, 1);
            }
            float r2[2];
#pragma unroll
            for (int i = 0; i < 2; ++i) {
                float keep = (lane & 2) ? r1[i + 2] : r1[i];
                float send = (lane & 2) ? r1[i] : r1[i + 2];
                r2[i] = keep + __shfl_xor(send, 2);
            }
            float keep = (lane & 4) ? r2[1] : r2[0];
            float send = (lane & 4) ? r2[0] : r2[1];
            float sv = keep + __shfl_xor(send, 4);
            sv += __shfl_xor(sv, 8);
            sv += __shfl_xor(sv, 16);
            sv += __shfl_xor(sv, 32);
            if (lane < 8)
                ssb[((lane & 1) << 2) | (lane & 2) | ((lane & 4) >> 2)][w] = sv;
            float s8 = ssv[8];
#pragma unroll
            for (int m = 1; m < 64; m <<= 1) s8 += __shfl_xor(s8, m);
            if (lane == 0) ssb[8][w] = s8;
        }

        __syncthreads();   // red + ssb visible

        // ---- normalize + bias -> q/k vectors ----
        if (t < ROWS * 8) {
            int r = t >> 3, hh = t & 7;
            float dt = red[r][0][hh] + red[r][1][hh] + red[r][2][hh] + red[r][3][hh];
            float s  = ssb[r][0] + ssb[r][1] + ssb[r][2] + ssb[r][3];
            fin[t] = fmaf(dt, rsqrtf(s + EPS_F), bias);
        }

        __syncthreads();   // fin visible

        // ---- scores + softmax (tiny serial tail; overlaps next iter's loads) ----
        if (t == 0) {
            float qv[8], sc[8];
#pragma unroll
            for (int i = 0; i < 8; ++i) qv[i] = fin[i];
            float mx = -1e30f;
#pragma unroll
            for (int n = 0; n < 8; ++n) {
                float s = 0.f;
#pragma unroll
                for (int i = 0; i < 8; ++i) s = fmaf(qv[i], fin[(n + 1) * 8 + i], s);
                s *= SCALE_F;
                sc[n] = s;
                mx = fmaxf(mx, s);
            }
            float den = 0.f;
#pragma unroll
            for (int n = 0; n < 8; ++n) {
                sc[n] = __expf(sc[n] - mx);
                den += sc[n];
            }
            float inv = 1.f / den;
            float4* op = (float4*)(out + (long)p * 8);
            op[0] = make_float4(sc[0] * inv, sc[1] * inv, sc[2] * inv, sc[3] * inv);
            op[1] = make_float4(sc[4] * inv, sc[5] * inv, sc[6] * inv, sc[7] * inv);
        }
    }
}

extern "C" void kernel_launch(void* const* d_in, const int* in_sizes, int n_in,
                              void* d_out, int out_size, void* d_ws, size_t ws_size,
                              hipStream_t stream) {
    const float* x   = (const float*)d_in[0];
    const float* bax = (const float*)d_in[1];
    const float* Wq  = (const float*)d_in[2];
    const float* bq  = (const float*)d_in[3];
    const float* Wk  = (const float*)d_in[4];
    const float* bk  = (const float*)d_in[5];
    float* out = (float*)d_out;

    const int positions = in_sizes[0] / DIN;   // B*S
    int nb = positions < 512 ? positions : 512;
    router_kernel<<<nb, 256, 0, stream>>>(x, bax, Wq, bq, Wk, bk, out, positions);
}